// Round 6
// baseline (543.644 us; speedup 1.0000x reference)
//
#include <hip/hip_runtime.h>
#include <math.h>

// SSMInterBlock fused v3: spill elimination.
// R4 evidence: VGPR_Count=64 + 925 MB HBM traffic = P-A live set spilled to
// scratch (713 B/thread matches acc+xv spill/fill per iter). v3: P-A split
// into 2 passes of 3 columns (peak live ~48-60 VGPRs) + amdgpu_waves_per_eu(4,5)
// pins the allocator budget to >=102 VGPRs (LDS caps residency at 5 blocks/CU
// anyway, so 8-wave targets are unreachable). DS-drain structure from v2 kept.

#define THREADS 256
#define SEQ_PB  4
#define DM      96
#define DE      192
#define NJ      384
#define NST     16
#define RNK     6
#define NC      38
#define XZS     1540   // per-seq pitch in s_xz (floats)
#define XDS     164    // per-seq pitch of x_dbl (floats)

// d_ws float offsets
#define OFF_WT1  0                      // [96][384]: wt1[dd][j] = w_in[j][dd]
#define OFF_XPW  36864                  // [192][40]: xpwT[d][c] = w_xp[c][d]
#define OFF_NA   (36864 + 7680)         // [192][16]: -exp(A_logs)
#define OFF_WO   (36864 + 7680 + 3072)  // [192][96]: wout[d][dd] = w_out[dd][d]

__device__ __forceinline__ float softplus_f(float x) {
    return fmaxf(x, 0.f) + log1pf(__expf(-fabsf(x)));
}
__device__ __forceinline__ float silu_f(float x) {
    return x / (1.f + __expf(-x));
}

__global__ void prep_weights(const float* __restrict__ w_in,
                             const float* __restrict__ w_xp,
                             const float* __restrict__ a_logs,
                             const float* __restrict__ w_out,
                             float* __restrict__ ws) {
    int t0 = blockIdx.x * blockDim.x + threadIdx.x;
    int stride = gridDim.x * blockDim.x;
    for (int t = t0; t < DM * NJ; t += stride) {          // W1^T
        int dd = t / NJ, j = t % NJ;
        ws[OFF_WT1 + t] = w_in[j * DM + dd];
    }
    for (int t = t0; t < DE * NC; t += stride) {          // xpw^T (pitch 40)
        int d = t / NC, c = t % NC;
        ws[OFF_XPW + d * 40 + c] = w_xp[c * DE + d];
    }
    for (int t = t0; t < DE * NST; t += stride)           // -exp(A_logs)
        ws[OFF_NA + t] = -__expf(a_logs[t]);
    for (int t = t0; t < DE * DM; t += stride) {          // Wout^T
        int d = t / DM, dd = t % DM;
        ws[OFF_WO + t] = w_out[dd * DE + d];
    }
}

__global__ __attribute__((amdgpu_waves_per_eu(4, 5))) __launch_bounds__(THREADS)
void ssm_fused3(const float* __restrict__ x,       // [nseq][384] = [seq][d][l]
                const float* __restrict__ w_dt,    // [192][6]
                const float* __restrict__ b_dt,    // [192]
                const float* __restrict__ dvec,    // [192]
                const float* __restrict__ gamma_,  // [192]
                const float* __restrict__ beta_,   // [192]
                const float* __restrict__ ws,      // transposed weights
                float* __restrict__ out)           // [nseq][384] = [seq][dd][l]
{
    __shared__ float s_xz[SEQ_PB * XZS];   // 24,640 B: u|z, then y, then yz
    __shared__ float s_xd[SEQ_PB * XDS];   //  2,624 B: x_dbl
    __shared__ float s_st[32];             //    128 B: LN mu/rstd

    const int tid  = threadIdx.x;
    const int lane = tid & 63;
    const int blk  = blockIdx.x;
    const int wv   = __builtin_amdgcn_readfirstlane(tid >> 6);  // wave id = seq

    // ---------- P-A: xz = silu(x @ W1^T). wave=seq. Two passes of 3 columns
    // keep live regs ~48 (acc 12 + xv 16 + in-flight w) -> no spill.
    {
        const float4* xs4 = (const float4*)(x + ((size_t)blk * SEQ_PB + wv) * NJ);
        #pragma unroll 1
        for (int pass = 0; pass < 2; ++pass) {
            const float* wbase = ws + OFF_WT1 + pass * 192 + lane;
            float acc[3][4];
            #pragma unroll
            for (int m = 0; m < 3; ++m) {
                acc[m][0] = 0.f; acc[m][1] = 0.f; acc[m][2] = 0.f; acc[m][3] = 0.f;
            }
            #pragma unroll 1
            for (int dds = 0; dds < DM; dds += 4) {
                float4 xv[4];
                #pragma unroll
                for (int i = 0; i < 4; ++i) xv[i] = xs4[dds + i];  // uniform -> s_load
                #pragma unroll
                for (int i = 0; i < 4; ++i) {
                    const float* wrow = wbase + (dds + i) * NJ;
                    #pragma unroll
                    for (int m = 0; m < 3; ++m) {
                        float w = wrow[m * 64];
                        acc[m][0] = fmaf(w, xv[i].x, acc[m][0]);
                        acc[m][1] = fmaf(w, xv[i].y, acc[m][1]);
                        acc[m][2] = fmaf(w, xv[i].z, acc[m][2]);
                        acc[m][3] = fmaf(w, xv[i].w, acc[m][3]);
                    }
                }
            }
            #pragma unroll
            for (int m = 0; m < 3; ++m) {
                int j = pass * 192 + m * 64 + lane;
                float4 sv;
                sv.x = silu_f(acc[m][0]); sv.y = silu_f(acc[m][1]);
                sv.z = silu_f(acc[m][2]); sv.w = silu_f(acc[m][3]);
                *(float4*)&s_xz[wv * XZS + j * 4] = sv;   // contiguous b128
            }
        }
    }
    __syncthreads();

    // ---------- P-B: x_dbl[c][l] = sum_d u[d][l] * xpw[c][d]
    if (tid < SEQ_PB * NC) {
        int seq = tid & 3, c = tid >> 2;
        const float* wc = ws + OFF_XPW + c;           // element (d,c) at d*40+c
        const float* uz = &s_xz[seq * XZS];
        float a0 = 0.f, a1 = 0.f, a2 = 0.f, a3 = 0.f;
        for (int d = 0; d < DE; ++d) {
            float w  = wc[d * 40];
            float4 u = *(const float4*)&uz[d * 4];
            a0 = fmaf(w, u.x, a0); a1 = fmaf(w, u.y, a1);
            a2 = fmaf(w, u.z, a2); a3 = fmaf(w, u.w, a3);
        }
        *(float4*)&s_xd[seq * XDS + c * 4] = make_float4(a0, a1, a2, a3);
    }
    __syncthreads();

    // ---------- P-C: delta + selective scan (n outer, h scalar); y in place
    #pragma unroll 1
    for (int rr = 0; rr < 3; ++rr) {
        int p = tid + rr * THREADS;
        int seq = p & 3, d = p >> 2;
        float4 u4 = *(const float4*)&s_xz[seq * XZS + d * 4];
        const float* xd = &s_xd[seq * XDS];

        const float2* wdt2 = (const float2*)(w_dt + d * RNK);  // 24B-aligned
        float2 wp0 = wdt2[0], wp1 = wdt2[1], wp2 = wdt2[2];
        float wr6[6] = {wp0.x, wp0.y, wp1.x, wp1.y, wp2.x, wp2.y};
        float d0 = 0.f, d1 = 0.f, d2 = 0.f, d3 = 0.f;
        #pragma unroll
        for (int r = 0; r < RNK; ++r) {
            float w  = wr6[r];
            float4 t = *(const float4*)&xd[r * 4];
            d0 = fmaf(w, t.x, d0); d1 = fmaf(w, t.y, d1);
            d2 = fmaf(w, t.z, d2); d3 = fmaf(w, t.w, d3);
        }
        float bias = b_dt[d];
        float dl0 = softplus_f(d0 + bias), dl1 = softplus_f(d1 + bias);
        float dl2 = softplus_f(d2 + bias), dl3 = softplus_f(d3 + bias);
        float du0 = dl0 * u4.x, du1 = dl1 * u4.y;
        float du2 = dl2 * u4.z, du3 = dl3 * u4.w;

        const float* nA = ws + OFF_NA + d * NST;
        float y0 = 0.f, y1 = 0.f, y2 = 0.f, y3 = 0.f;
        #pragma unroll
        for (int n = 0; n < NST; ++n) {
            float an = nA[n];
            float4 bn = *(const float4*)&xd[(RNK + n) * 4];
            float4 cn = *(const float4*)&xd[(RNK + NST + n) * 4];
            float h = du0 * bn.x;                        // l=0
            y0 = fmaf(h, cn.x, y0);
            h = fmaf(du1, bn.y, __expf(dl1 * an) * h);   // l=1
            y1 = fmaf(h, cn.y, y1);
            h = fmaf(du2, bn.z, __expf(dl2 * an) * h);   // l=2
            y2 = fmaf(h, cn.z, y2);
            h = fmaf(du3, bn.w, __expf(dl3 * an) * h);   // l=3
            y3 = fmaf(h, cn.w, y3);
        }
        float Dd = dvec[d];
        float4 yo;
        yo.x = fmaf(Dd, u4.x, y0); yo.y = fmaf(Dd, u4.y, y1);
        yo.z = fmaf(Dd, u4.z, y2); yo.w = fmaf(Dd, u4.w, y3);
        *(float4*)&s_xz[seq * XZS + d * 4] = yo;
    }
    __syncthreads();

    // ---------- P-LN: per (seq,l) mean/rstd over De=192
    {
        int g = tid >> 4, i = tid & 15;
        int seq = g >> 2, l = g & 3;
        float s = 0.f, ss = 0.f;
        #pragma unroll
        for (int k = 0; k < DE / 16; ++k) {
            float v = s_xz[seq * XZS + (i + k * 16) * 4 + l];
            s += v; ss = fmaf(v, v, ss);
        }
        #pragma unroll
        for (int off = 1; off < 16; off <<= 1) {
            s  += __shfl_xor(s,  off, 16);
            ss += __shfl_xor(ss, off, 16);
        }
        if (i == 0) {
            float mu  = s * (1.f / DE);
            float var = ss * (1.f / DE) - mu * mu;
            s_st[g]      = mu;
            s_st[16 + g] = rsqrtf(var + 1e-5f);
        }
    }
    __syncthreads();

    // ---------- P-LN2: yz = ((y-mu)*rstd*gamma + beta) * z, in place
    #pragma unroll 1
    for (int rr = 0; rr < 3; ++rr) {
        int p = tid + rr * THREADS;
        int seq = p & 3, d = p >> 2;
        float4 y4  = *(const float4*)&s_xz[seq * XZS + d * 4];
        float4 z4  = *(const float4*)&s_xz[seq * XZS + (DE + d) * 4];
        float4 mu4 = *(const float4*)&s_st[seq * 4];
        float4 rs4 = *(const float4*)&s_st[16 + seq * 4];
        float ga = gamma_[d], be = beta_[d];
        float4 o;
        o.x = fmaf((y4.x - mu4.x) * rs4.x, ga, be) * z4.x;
        o.y = fmaf((y4.y - mu4.y) * rs4.y, ga, be) * z4.y;
        o.z = fmaf((y4.z - mu4.z) * rs4.z, ga, be) * z4.z;
        o.w = fmaf((y4.w - mu4.w) * rs4.w, ga, be) * z4.w;
        *(float4*)&s_xz[seq * XZS + d * 4] = o;
    }
    __syncthreads();

    // ---------- P-D: out[dd][l] = sum_d yz[d][l] * wout[dd][d]; wave=seq
    {
        const int dd1 = lane;              // 0..63
        const int dd2 = 64 + (lane & 31);  // 64..95 (upper half duplicates, masked store)
        const float* wo  = ws + OFF_WO;
        const float* yzp = &s_xz[wv * XZS];
        float a1_[4] = {0.f, 0.f, 0.f, 0.f};
        float a2_[4] = {0.f, 0.f, 0.f, 0.f};
        #pragma unroll 4
        for (int d = 0; d < DE; ++d) {
            float4 yz = *(const float4*)&yzp[d * 4];   // single-address b128 broadcast
            float w1 = wo[d * DM + dd1];               // coalesced global
            float w2 = wo[d * DM + dd2];
            a1_[0] = fmaf(w1, yz.x, a1_[0]); a1_[1] = fmaf(w1, yz.y, a1_[1]);
            a1_[2] = fmaf(w1, yz.z, a1_[2]); a1_[3] = fmaf(w1, yz.w, a1_[3]);
            a2_[0] = fmaf(w2, yz.x, a2_[0]); a2_[1] = fmaf(w2, yz.y, a2_[1]);
            a2_[2] = fmaf(w2, yz.z, a2_[2]); a2_[3] = fmaf(w2, yz.w, a2_[3]);
        }
        float* ob = out + (size_t)blk * (SEQ_PB * NJ) + wv * NJ;
        *(float4*)&ob[dd1 * 4] = make_float4(a1_[0], a1_[1], a1_[2], a1_[3]);
        if (lane < 32)
            *(float4*)&ob[dd2 * 4] = make_float4(a2_[0], a2_[1], a2_[2], a2_[3]);
    }
}

extern "C" void kernel_launch(void* const* d_in, const int* in_sizes, int n_in,
                              void* d_out, int out_size, void* d_ws, size_t ws_size,
                              hipStream_t stream) {
    (void)n_in; (void)ws_size; (void)out_size;
    int nseq = in_sizes[0] / NJ;            // 12544 = 4*56*56
    int grid = nseq / SEQ_PB;               // 3136 blocks
    if (grid < 1) grid = 1;
    float* ws = (float*)d_ws;               // needs 264 KB

    prep_weights<<<64, THREADS, 0, stream>>>(
        (const float*)d_in[1],  // in_proj_w
        (const float*)d_in[2],  // x_proj_weight
        (const float*)d_in[5],  // A_logs
        (const float*)d_in[9],  // out_proj_w
        ws);

    ssm_fused3<<<grid, THREADS, 0, stream>>>(
        (const float*)d_in[0],  // x
        (const float*)d_in[3],  // dt_projs_weight
        (const float*)d_in[4],  // dt_projs_bias
        (const float*)d_in[6],  // Ds
        (const float*)d_in[7],  // ln_gamma
        (const float*)d_in[8],  // ln_beta
        ws,
        (float*)d_out);
}

// Round 7
// 526.436 us; speedup vs baseline: 1.0327x; 1.0327x over previous
//
#include <hip/hip_runtime.h>
#include <math.h>

// SSMInterBlock fused v4: scratch-array elimination.
// R4/R6 evidence: WRITE ~600 MB (25 KB real) in both v2 and v3, VGPR pinned at
// 64 despite 128 budget, FETCH = full weight set per block (L2 reuse destroyed).
// Common factor: small fp32 C arrays (acc[][], xv[], wr6[]) demoted to scratch
// by the compiler (v1 with named scalars had no such traffic). v4: NO arrays --
// every accumulator is a named float4/scalar. P-A back to single W1^T sweep
// (v3's 2-pass split doubled weight FETCH). DS-drain structure from v2 kept.

#define THREADS 256
#define SEQ_PB  4
#define DM      96
#define DE      192
#define NJ      384
#define NST     16
#define RNK     6
#define NC      38
#define XZS     1540   // per-seq pitch in s_xz (floats)
#define XDS     164    // per-seq pitch of x_dbl (floats)

// d_ws float offsets
#define OFF_WT1  0                      // [96][384]: wt1[dd][j] = w_in[j][dd]
#define OFF_XPW  36864                  // [192][40]: xpwT[d][c] = w_xp[c][d]
#define OFF_NA   (36864 + 7680)         // [192][16]: -exp(A_logs)
#define OFF_WO   (36864 + 7680 + 3072)  // [192][96]: wout[d][dd] = w_out[dd][d]

__device__ __forceinline__ float softplus_f(float x) {
    return fmaxf(x, 0.f) + log1pf(__expf(-fabsf(x)));
}
__device__ __forceinline__ float silu_f(float x) {
    return x / (1.f + __expf(-x));
}
__device__ __forceinline__ float4 fma4(float w, float4 x, float4 a) {
    a.x = fmaf(w, x.x, a.x); a.y = fmaf(w, x.y, a.y);
    a.z = fmaf(w, x.z, a.z); a.w = fmaf(w, x.w, a.w);
    return a;
}

__global__ void prep_weights(const float* __restrict__ w_in,
                             const float* __restrict__ w_xp,
                             const float* __restrict__ a_logs,
                             const float* __restrict__ w_out,
                             float* __restrict__ ws) {
    int t0 = blockIdx.x * blockDim.x + threadIdx.x;
    int stride = gridDim.x * blockDim.x;
    for (int t = t0; t < DM * NJ; t += stride) {          // W1^T
        int dd = t / NJ, j = t % NJ;
        ws[OFF_WT1 + t] = w_in[j * DM + dd];
    }
    for (int t = t0; t < DE * NC; t += stride) {          // xpw^T (pitch 40)
        int d = t / NC, c = t % NC;
        ws[OFF_XPW + d * 40 + c] = w_xp[c * DE + d];
    }
    for (int t = t0; t < DE * NST; t += stride)           // -exp(A_logs)
        ws[OFF_NA + t] = -__expf(a_logs[t]);
    for (int t = t0; t < DE * DM; t += stride) {          // Wout^T
        int d = t / DM, dd = t % DM;
        ws[OFF_WO + t] = w_out[dd * DE + d];
    }
}

__global__ __launch_bounds__(THREADS, 4)
void ssm_fused4(const float* __restrict__ x,       // [nseq][384] = [seq][d][l]
                const float* __restrict__ w_dt,    // [192][6]
                const float* __restrict__ b_dt,    // [192]
                const float* __restrict__ dvec,    // [192]
                const float* __restrict__ gamma_,  // [192]
                const float* __restrict__ beta_,   // [192]
                const float* __restrict__ ws,      // transposed weights
                float* __restrict__ out)           // [nseq][384] = [seq][dd][l]
{
    __shared__ float s_xz[SEQ_PB * XZS];   // 24,640 B: u|z, then y, then yz
    __shared__ float s_xd[SEQ_PB * XDS];   //  2,624 B: x_dbl
    __shared__ float s_st[32];             //    128 B: LN mu/rstd

    const int tid  = threadIdx.x;
    const int lane = tid & 63;
    const int blk  = blockIdx.x;
    const int wv   = __builtin_amdgcn_readfirstlane(tid >> 6);  // wave id = seq

    // ---------- P-A: xz = silu(x @ W1^T). wave=seq; lane+m cover j=m*64+lane.
    // Single sweep over dd; 6 named float4 accumulators (NO arrays -> no scratch).
    {
        const float4* xs4 = (const float4*)(x + ((size_t)blk * SEQ_PB + wv) * NJ);
        const float* wbase = ws + OFF_WT1 + lane;
        float4 zero4 = make_float4(0.f, 0.f, 0.f, 0.f);
        float4 acc0 = zero4, acc1 = zero4, acc2 = zero4;
        float4 acc3 = zero4, acc4 = zero4, acc5 = zero4;
        #pragma unroll 1
        for (int dds = 0; dds < DM; dds += 4) {
            float4 xv0 = xs4[dds + 0];
            float4 xv1 = xs4[dds + 1];
            float4 xv2 = xs4[dds + 2];
            float4 xv3 = xs4[dds + 3];
            const float* w0p = wbase + dds * NJ;
#define PA_STEP(XV, RO) { \
            const float* wr_ = w0p + (RO); \
            float w_; \
            w_ = wr_[0];   acc0 = fma4(w_, XV, acc0); \
            w_ = wr_[64];  acc1 = fma4(w_, XV, acc1); \
            w_ = wr_[128]; acc2 = fma4(w_, XV, acc2); \
            w_ = wr_[192]; acc3 = fma4(w_, XV, acc3); \
            w_ = wr_[256]; acc4 = fma4(w_, XV, acc4); \
            w_ = wr_[320]; acc5 = fma4(w_, XV, acc5); }
            PA_STEP(xv0, 0)
            PA_STEP(xv1, NJ)
            PA_STEP(xv2, 2 * NJ)
            PA_STEP(xv3, 3 * NJ)
#undef PA_STEP
        }
#define PA_OUT(ACC, M) { \
        float4 sv_; \
        sv_.x = silu_f(ACC.x); sv_.y = silu_f(ACC.y); \
        sv_.z = silu_f(ACC.z); sv_.w = silu_f(ACC.w); \
        *(float4*)&s_xz[wv * XZS + ((M) * 64 + lane) * 4] = sv_; }
        PA_OUT(acc0, 0) PA_OUT(acc1, 1) PA_OUT(acc2, 2)
        PA_OUT(acc3, 3) PA_OUT(acc4, 4) PA_OUT(acc5, 5)
#undef PA_OUT
    }
    __syncthreads();

    // ---------- P-B: x_dbl[c][l] = sum_d u[d][l] * xpw[c][d]
    if (tid < SEQ_PB * NC) {
        int seq = tid & 3, c = tid >> 2;
        const float* wc = ws + OFF_XPW + c;           // element (d,c) at d*40+c
        const float* uz = &s_xz[seq * XZS];
        float a0 = 0.f, a1 = 0.f, a2 = 0.f, a3 = 0.f;
        for (int d = 0; d < DE; ++d) {
            float w  = wc[d * 40];
            float4 u = *(const float4*)&uz[d * 4];
            a0 = fmaf(w, u.x, a0); a1 = fmaf(w, u.y, a1);
            a2 = fmaf(w, u.z, a2); a3 = fmaf(w, u.w, a3);
        }
        *(float4*)&s_xd[seq * XDS + c * 4] = make_float4(a0, a1, a2, a3);
    }
    __syncthreads();

    // ---------- P-C: delta + selective scan (n outer, h scalar); y in place
    #pragma unroll 1
    for (int rr = 0; rr < 3; ++rr) {
        int p = tid + rr * THREADS;
        int seq = p & 3, d = p >> 2;
        float4 u4 = *(const float4*)&s_xz[seq * XZS + d * 4];
        const float* xd = &s_xd[seq * XDS];

        const float2* wdt2 = (const float2*)(w_dt + d * RNK);  // 8B-aligned
        float2 wp0 = wdt2[0], wp1 = wdt2[1], wp2 = wdt2[2];
        float d0, d1, d2, d3;
        {
            float4 t0 = *(const float4*)&xd[0];
            float4 t1 = *(const float4*)&xd[4];
            float4 t2 = *(const float4*)&xd[8];
            float4 t3 = *(const float4*)&xd[12];
            float4 t4 = *(const float4*)&xd[16];
            float4 t5 = *(const float4*)&xd[20];
            d0 = wp0.x * t0.x; d1 = wp0.x * t0.y; d2 = wp0.x * t0.z; d3 = wp0.x * t0.w;
            d0 = fmaf(wp0.y, t1.x, d0); d1 = fmaf(wp0.y, t1.y, d1);
            d2 = fmaf(wp0.y, t1.z, d2); d3 = fmaf(wp0.y, t1.w, d3);
            d0 = fmaf(wp1.x, t2.x, d0); d1 = fmaf(wp1.x, t2.y, d1);
            d2 = fmaf(wp1.x, t2.z, d2); d3 = fmaf(wp1.x, t2.w, d3);
            d0 = fmaf(wp1.y, t3.x, d0); d1 = fmaf(wp1.y, t3.y, d1);
            d2 = fmaf(wp1.y, t3.z, d2); d3 = fmaf(wp1.y, t3.w, d3);
            d0 = fmaf(wp2.x, t4.x, d0); d1 = fmaf(wp2.x, t4.y, d1);
            d2 = fmaf(wp2.x, t4.z, d2); d3 = fmaf(wp2.x, t4.w, d3);
            d0 = fmaf(wp2.y, t5.x, d0); d1 = fmaf(wp2.y, t5.y, d1);
            d2 = fmaf(wp2.y, t5.z, d2); d3 = fmaf(wp2.y, t5.w, d3);
        }
        float bias = b_dt[d];
        float dl0 = softplus_f(d0 + bias), dl1 = softplus_f(d1 + bias);
        float dl2 = softplus_f(d2 + bias), dl3 = softplus_f(d3 + bias);
        float du0 = dl0 * u4.x, du1 = dl1 * u4.y;
        float du2 = dl2 * u4.z, du3 = dl3 * u4.w;

        const float* nA = ws + OFF_NA + d * NST;
        float y0 = 0.f, y1 = 0.f, y2 = 0.f, y3 = 0.f;
        #pragma unroll
        for (int n = 0; n < NST; ++n) {
            float an = nA[n];
            float4 bn = *(const float4*)&xd[(RNK + n) * 4];
            float4 cn = *(const float4*)&xd[(RNK + NST + n) * 4];
            float h = du0 * bn.x;                        // l=0
            y0 = fmaf(h, cn.x, y0);
            h = fmaf(du1, bn.y, __expf(dl1 * an) * h);   // l=1
            y1 = fmaf(h, cn.y, y1);
            h = fmaf(du2, bn.z, __expf(dl2 * an) * h);   // l=2
            y2 = fmaf(h, cn.z, y2);
            h = fmaf(du3, bn.w, __expf(dl3 * an) * h);   // l=3
            y3 = fmaf(h, cn.w, y3);
        }
        float Dd = dvec[d];
        float4 yo;
        yo.x = fmaf(Dd, u4.x, y0); yo.y = fmaf(Dd, u4.y, y1);
        yo.z = fmaf(Dd, u4.z, y2); yo.w = fmaf(Dd, u4.w, y3);
        *(float4*)&s_xz[seq * XZS + d * 4] = yo;
    }
    __syncthreads();

    // ---------- P-LN: per (seq,l) mean/rstd over De=192
    {
        int g = tid >> 4, i = tid & 15;
        int seq = g >> 2, l = g & 3;
        float s = 0.f, ss = 0.f;
        #pragma unroll
        for (int k = 0; k < DE / 16; ++k) {
            float v = s_xz[seq * XZS + (i + k * 16) * 4 + l];
            s += v; ss = fmaf(v, v, ss);
        }
        #pragma unroll
        for (int off = 1; off < 16; off <<= 1) {
            s  += __shfl_xor(s,  off, 16);
            ss += __shfl_xor(ss, off, 16);
        }
        if (i == 0) {
            float mu  = s * (1.f / DE);
            float var = ss * (1.f / DE) - mu * mu;
            s_st[g]      = mu;
            s_st[16 + g] = rsqrtf(var + 1e-5f);
        }
    }
    __syncthreads();

    // ---------- P-LN2: yz = ((y-mu)*rstd*gamma + beta) * z, in place
    #pragma unroll 1
    for (int rr = 0; rr < 3; ++rr) {
        int p = tid + rr * THREADS;
        int seq = p & 3, d = p >> 2;
        float4 y4  = *(const float4*)&s_xz[seq * XZS + d * 4];
        float4 z4  = *(const float4*)&s_xz[seq * XZS + (DE + d) * 4];
        float4 mu4 = *(const float4*)&s_st[seq * 4];
        float4 rs4 = *(const float4*)&s_st[16 + seq * 4];
        float ga = gamma_[d], be = beta_[d];
        float4 o;
        o.x = fmaf((y4.x - mu4.x) * rs4.x, ga, be) * z4.x;
        o.y = fmaf((y4.y - mu4.y) * rs4.y, ga, be) * z4.y;
        o.z = fmaf((y4.z - mu4.z) * rs4.z, ga, be) * z4.z;
        o.w = fmaf((y4.w - mu4.w) * rs4.w, ga, be) * z4.w;
        *(float4*)&s_xz[seq * XZS + d * 4] = o;
    }
    __syncthreads();

    // ---------- P-D: out[dd][l] = sum_d yz[d][l] * wout[dd][d]; wave=seq
    {
        const int dd1 = lane;              // 0..63
        const int dd2 = 64 + (lane & 31);  // 64..95 (upper half duplicates, masked store)
        const float* wo  = ws + OFF_WO;
        const float* yzp = &s_xz[wv * XZS];
        float4 o1 = make_float4(0.f, 0.f, 0.f, 0.f);
        float4 o2 = make_float4(0.f, 0.f, 0.f, 0.f);
        #pragma unroll 4
        for (int d = 0; d < DE; ++d) {
            float4 yz = *(const float4*)&yzp[d * 4];   // single-address b128 broadcast
            float w1 = wo[d * DM + dd1];               // coalesced global
            float w2 = wo[d * DM + dd2];
            o1 = fma4(w1, yz, o1);
            o2 = fma4(w2, yz, o2);
        }
        float* ob = out + (size_t)blk * (SEQ_PB * NJ) + wv * NJ;
        *(float4*)&ob[dd1 * 4] = o1;
        if (lane < 32)
            *(float4*)&ob[dd2 * 4] = o2;
    }
}

extern "C" void kernel_launch(void* const* d_in, const int* in_sizes, int n_in,
                              void* d_out, int out_size, void* d_ws, size_t ws_size,
                              hipStream_t stream) {
    (void)n_in; (void)ws_size; (void)out_size;
    int nseq = in_sizes[0] / NJ;            // 12544 = 4*56*56
    int grid = nseq / SEQ_PB;               // 3136 blocks
    if (grid < 1) grid = 1;
    float* ws = (float*)d_ws;               // needs 264 KB

    prep_weights<<<64, THREADS, 0, stream>>>(
        (const float*)d_in[1],  // in_proj_w
        (const float*)d_in[2],  // x_proj_weight
        (const float*)d_in[5],  // A_logs
        (const float*)d_in[9],  // out_proj_w
        ws);

    ssm_fused4<<<grid, THREADS, 0, stream>>>(
        (const float*)d_in[0],  // x
        (const float*)d_in[3],  // dt_projs_weight
        (const float*)d_in[4],  // dt_projs_bias
        (const float*)d_in[6],  // Ds
        (const float*)d_in[7],  // ln_gamma
        (const float*)d_in[8],  // ln_beta
        ws,
        (float*)d_out);
}